// Round 5
// baseline (497.355 us; speedup 1.0000x reference)
//
#include <hip/hip_runtime.h>
#include <hip/hip_bf16.h>

#define IN_DIM 128
#define HID    64
#define OUTF   16
#define NGRAPH 500

// ---------------- GEMM: H[N,F] = X[N,K] @ W[K,F] ----------------
template<int K, int F>
__global__ __launch_bounds__(256) void gemm_kernel(const float* __restrict__ X,
                                                   const float* __restrict__ W,
                                                   float* __restrict__ H, int N) {
    constexpr int C4 = F / 4;          // float4 cols
    constexpr int ROWS = 256 / C4;     // rows per block
    constexpr int K4 = K / 4;
    __shared__ float4 sW[K * C4];
    __shared__ float4 sX4[ROWS * K4];
    const int tid = threadIdx.x;
    const float4* W4 = (const float4*)W;
    for (int i = tid; i < K * C4; i += 256) sW[i] = W4[i];
    const int row0 = blockIdx.x * ROWS;
    const float4* X4 = (const float4*)X;
    for (int i = tid; i < ROWS * K4; i += 256) {
        int r = i / K4, kk = i - r * K4;
        int gr = row0 + r;
        float4 z = {0.f, 0.f, 0.f, 0.f};
        sX4[r * K4 + kk] = (gr < N) ? X4[(long long)gr * K4 + kk] : z;
    }
    __syncthreads();
    const int r = tid / C4, c4 = tid - (tid / C4) * C4;
    const float* sXr = (const float*)&sX4[r * K4];
    float4 acc = {0.f, 0.f, 0.f, 0.f};
#pragma unroll
    for (int k = 0; k < K; ++k) {
        float xv = sXr[k];
        float4 wv = sW[k * C4 + c4];
        acc.x += xv * wv.x; acc.y += xv * wv.y;
        acc.z += xv * wv.z; acc.w += xv * wv.w;
    }
    const int gr = row0 + r;
    if (gr < N) ((float4*)H)[(long long)gr * C4 + c4] = acc;
}

// ---------------- fused: CSR fill (blocks [0,fillBlocks)) + gemm1 (rest) ------
// fill is memory-system throughput-bound with all pipes idle (R4: VALUBusy
// 0.2%, HBM 12%); gemm1 is the only dispatch independent of the CSR chain, so
// co-schedule them in one launch. Fill blocks first so they start immediately.
__global__ __launch_bounds__(256) void fill_gemm_kernel(
        const int* __restrict__ src, const int* __restrict__ dst,
        int* __restrict__ rowptr, int* __restrict__ csr_src, int E, int fillBlocks,
        const float* __restrict__ X, const float* __restrict__ W,
        float* __restrict__ H, int N) {
    constexpr int K = IN_DIM, F = HID;
    constexpr int C4 = F / 4, ROWS = 256 / C4, K4 = K / 4;
    __shared__ float4 sW[K * C4];
    __shared__ float4 sX4[ROWS * K4];
    const int tid = threadIdx.x;

    if (blockIdx.x < fillBlocks) {
        constexpr int EPT = 4;
        int base = blockIdx.x * (256 * EPT) + tid;
        if (base + (EPT - 1) * 256 < E) {
            int s[EPT], d[EPT], pos[EPT];
#pragma unroll
            for (int k = 0; k < EPT; ++k) {
                d[k] = dst[base + k * 256];
                s[k] = src[base + k * 256];
            }
#pragma unroll
            for (int k = 0; k < EPT; ++k) pos[k] = atomicAdd(&rowptr[d[k]], 1);
#pragma unroll
            for (int k = 0; k < EPT; ++k) csr_src[pos[k]] = s[k];
        } else {
#pragma unroll
            for (int k = 0; k < EPT; ++k) {
                int e = base + k * 256;
                if (e < E) {
                    int pos = atomicAdd(&rowptr[dst[e]], 1);
                    csr_src[pos] = src[e];
                }
            }
        }
        return;
    }

    const int bid = blockIdx.x - fillBlocks;
    const float4* W4 = (const float4*)W;
    for (int i = tid; i < K * C4; i += 256) sW[i] = W4[i];
    const int row0 = bid * ROWS;
    const float4* X4 = (const float4*)X;
    for (int i = tid; i < ROWS * K4; i += 256) {
        int r = i / K4, kk = i - r * K4;
        int gr = row0 + r;
        float4 z = {0.f, 0.f, 0.f, 0.f};
        sX4[r * K4 + kk] = (gr < N) ? X4[(long long)gr * K4 + kk] : z;
    }
    __syncthreads();
    const int r = tid / C4, c4 = tid - (tid / C4) * C4;
    const float* sXr = (const float*)&sX4[r * K4];
    float4 acc = {0.f, 0.f, 0.f, 0.f};
#pragma unroll
    for (int k = 0; k < K; ++k) {
        float xv = sXr[k];
        float4 wv = sW[k * C4 + c4];
        acc.x += xv * wv.x; acc.y += xv * wv.y;
        acc.z += xv * wv.z; acc.w += xv * wv.w;
    }
    const int gr = row0 + r;
    if (gr < N) ((float4*)H)[(long long)gr * C4 + c4] = acc;
}

// ---------------- degree (int), EPT edges/thread ----------------
template<int EPT>
__global__ __launch_bounds__(256) void deg_kernel(const int* __restrict__ dst,
                                                  int* __restrict__ degi, int E) {
    int base = blockIdx.x * (256 * EPT) + threadIdx.x;
    if (base + (EPT - 1) * 256 < E) {
        int d[EPT];
#pragma unroll
        for (int k = 0; k < EPT; ++k) d[k] = dst[base + k * 256];
#pragma unroll
        for (int k = 0; k < EPT; ++k) atomicAdd(&degi[d[k]], 1);
    } else {
#pragma unroll
        for (int k = 0; k < EPT; ++k) {
            int e = base + k * 256;
            if (e < E) atomicAdd(&degi[dst[e]], 1);
        }
    }
}

// ---------------- scan1: exclusive block-scan of degi; also emits dis ----------
__global__ __launch_bounds__(1024) void scan1_kernel(const int* __restrict__ degi,
                                                     int* __restrict__ rowptr,
                                                     int* __restrict__ aux,
                                                     float* __restrict__ dis, int N) {
    __shared__ int s[1024];
    int i = blockIdx.x * 1024 + threadIdx.x;
    int v = (i < N) ? degi[i] : 0;
    if (i < N) dis[i] = rsqrtf(1.0f + (float)v);
    s[threadIdx.x] = v;
    __syncthreads();
    for (int off = 1; off < 1024; off <<= 1) {
        int t = (threadIdx.x >= off) ? s[threadIdx.x - off] : 0;
        __syncthreads();
        s[threadIdx.x] += t;
        __syncthreads();
    }
    if (i < N) rowptr[i] = s[threadIdx.x] - v;          // exclusive
    if (threadIdx.x == 1023) aux[blockIdx.x] = s[1023]; // block total
}

__global__ __launch_bounds__(128) void scan2_kernel(int* __restrict__ aux, int nb) {
    __shared__ int s[128];
    int v = (threadIdx.x < nb) ? aux[threadIdx.x] : 0;
    s[threadIdx.x] = v;
    __syncthreads();
    for (int off = 1; off < 128; off <<= 1) {
        int t = (threadIdx.x >= off) ? s[threadIdx.x - off] : 0;
        __syncthreads();
        s[threadIdx.x] += t;
        __syncthreads();
    }
    if (threadIdx.x < nb) aux[threadIdx.x] = s[threadIdx.x] - v; // exclusive
}

__global__ __launch_bounds__(1024) void scan3_kernel(int* __restrict__ rowptr,
                                                     const int* __restrict__ aux, int N) {
    int i = blockIdx.x * 1024 + threadIdx.x;
    if (i < N) rowptr[i] += aux[blockIdx.x];
}

// ---------------- fused aggregate + self-loop + bias [+ relu], F=64 ----------------
// Wave = one node. 16 edge-groups x 4 lanes x 4 float4/lane: 16 edges in
// flight per round -> avg-degree-12 row gathers in ONE round.
template<bool RELU>
__global__ __launch_bounds__(256) void agg64_kernel(const float4* __restrict__ H4,
                                                    const int* __restrict__ rowptr,
                                                    const int* __restrict__ csr_src,
                                                    const float* __restrict__ dis,
                                                    const float4* __restrict__ b4,
                                                    float4* __restrict__ out4, int N) {
    int node = blockIdx.x * 4 + (threadIdx.x >> 6);
    int lane = threadIdx.x & 63;
    int g = lane >> 2, c = lane & 3;   // 16 groups, 4 chunk-lanes
    if (node >= N) return;
    float dd = dis[node];
    int i0 = (node == 0) ? 0 : rowptr[node - 1];
    int i1 = rowptr[node];
    float4 a0 = {0.f,0.f,0.f,0.f}, a1 = {0.f,0.f,0.f,0.f};
    float4 a2 = {0.f,0.f,0.f,0.f}, a3 = {0.f,0.f,0.f,0.f};
    for (int i = i0 + g; i < i1; i += 16) {
        int s = csr_src[i];
        float w = dis[s] * dd;
        const float4* row = H4 + (long long)s * 16;
        float4 v0 = row[c], v1 = row[c + 4], v2 = row[c + 8], v3 = row[c + 12];
        a0.x += v0.x * w; a0.y += v0.y * w; a0.z += v0.z * w; a0.w += v0.w * w;
        a1.x += v1.x * w; a1.y += v1.y * w; a1.z += v1.z * w; a1.w += v1.w * w;
        a2.x += v2.x * w; a2.y += v2.y * w; a2.z += v2.z * w; a2.w += v2.w * w;
        a3.x += v3.x * w; a3.y += v3.y * w; a3.z += v3.z * w; a3.w += v3.w * w;
    }
#pragma unroll
    for (int m = 4; m <= 32; m <<= 1) {
        a0.x += __shfl_xor(a0.x, m); a0.y += __shfl_xor(a0.y, m);
        a0.z += __shfl_xor(a0.z, m); a0.w += __shfl_xor(a0.w, m);
        a1.x += __shfl_xor(a1.x, m); a1.y += __shfl_xor(a1.y, m);
        a1.z += __shfl_xor(a1.z, m); a1.w += __shfl_xor(a1.w, m);
        a2.x += __shfl_xor(a2.x, m); a2.y += __shfl_xor(a2.y, m);
        a2.z += __shfl_xor(a2.z, m); a2.w += __shfl_xor(a2.w, m);
        a3.x += __shfl_xor(a3.x, m); a3.y += __shfl_xor(a3.y, m);
        a3.z += __shfl_xor(a3.z, m); a3.w += __shfl_xor(a3.w, m);
    }
    if (g == 0) {
        float sl = dd * dd;
        const float4* hrow = H4 + (long long)node * 16;
        float4* orow = out4 + (long long)node * 16;
#pragma unroll
        for (int j = 0; j < 4; ++j) {
            float4 a = (j == 0) ? a0 : (j == 1) ? a1 : (j == 2) ? a2 : a3;
            float4 h = hrow[c + 4 * j];
            float4 bb = b4[c + 4 * j];
            a.x += h.x * sl + bb.x; a.y += h.y * sl + bb.y;
            a.z += h.z * sl + bb.z; a.w += h.w * sl + bb.w;
            if (RELU) {
                a.x = fmaxf(a.x, 0.f); a.y = fmaxf(a.y, 0.f);
                a.z = fmaxf(a.z, 0.f); a.w = fmaxf(a.w, 0.f);
            }
            orow[c + 4 * j] = a;
        }
    }
}

// ---------------- F=16: 16 edge-groups x 4 chunks per wave ----------------
template<bool RELU>
__global__ __launch_bounds__(256) void agg16_kernel(const float4* __restrict__ H4,
                                                    const int* __restrict__ rowptr,
                                                    const int* __restrict__ csr_src,
                                                    const float* __restrict__ dis,
                                                    const float4* __restrict__ b4,
                                                    float4* __restrict__ out4, int N) {
    int node = blockIdx.x * 4 + (threadIdx.x >> 6);
    int lane = threadIdx.x & 63;
    int g = lane >> 2, c = lane & 3;
    if (node >= N) return;
    float dd = dis[node];
    int i0 = (node == 0) ? 0 : rowptr[node - 1];
    int i1 = rowptr[node];
    float4 acc = {0.f, 0.f, 0.f, 0.f};
    for (int i = i0 + g; i < i1; i += 16) {
        int s = csr_src[i];
        float w = dis[s] * dd;
        float4 v = H4[(long long)s * 4 + c];
        acc.x += v.x * w; acc.y += v.y * w;
        acc.z += v.z * w; acc.w += v.w * w;
    }
#pragma unroll
    for (int m = 4; m <= 32; m <<= 1) {
        acc.x += __shfl_xor(acc.x, m);
        acc.y += __shfl_xor(acc.y, m);
        acc.z += __shfl_xor(acc.z, m);
        acc.w += __shfl_xor(acc.w, m);
    }
    if (g == 0) {
        float4 h = H4[(long long)node * 4 + c];
        float sl = dd * dd;
        float4 bb = b4[c];
        acc.x += h.x * sl + bb.x; acc.y += h.y * sl + bb.y;
        acc.z += h.z * sl + bb.z; acc.w += h.w * sl + bb.w;
        if (RELU) {
            acc.x = fmaxf(acc.x, 0.f); acc.y = fmaxf(acc.y, 0.f);
            acc.z = fmaxf(acc.z, 0.f); acc.w = fmaxf(acc.w, 0.f);
        }
        out4[(long long)node * 4 + c] = acc;
    }
}

// ---------------- pooling: register runs -> LDS bins -> few global atomics ----
__global__ __launch_bounds__(256) void pool_kernel(const float4* __restrict__ H4,
                                                   const int* __restrict__ batch,
                                                   float* __restrict__ sums,
                                                   float* __restrict__ cnts, int N) {
    __shared__ float sBin[16][16];
    __shared__ float sCnt[16];
    const int t = threadIdx.x;
    sBin[t >> 4][t & 15] = 0.f;
    if (t < 16) sCnt[t] = 0.f;
    __syncthreads();
    const int n0 = blockIdx.x * 256;
    const int g0 = batch[n0];
    const int nl = t >> 2;     // node lane 0..63
    const int f4 = t & 3;      // float4 chunk 0..3
    float4 acc = {0.f, 0.f, 0.f, 0.f};
    float cnt = 0.f;
    int curli = -1;
    for (int j = 0; j < 4; ++j) {
        int node = n0 + nl * 4 + j;
        if (node >= N) break;
        int li = batch[node] - g0;
        if (li != curli) {
            if (curli >= 0) {
                if (curli < 16) {
                    float* bp = &sBin[curli][f4 * 4];
                    atomicAdd(bp + 0, acc.x); atomicAdd(bp + 1, acc.y);
                    atomicAdd(bp + 2, acc.z); atomicAdd(bp + 3, acc.w);
                    if (f4 == 0) atomicAdd(&sCnt[curli], cnt);
                } else {
                    float* gp = &sums[(g0 + curli) * OUTF + f4 * 4];
                    atomicAdd(gp + 0, acc.x); atomicAdd(gp + 1, acc.y);
                    atomicAdd(gp + 2, acc.z); atomicAdd(gp + 3, acc.w);
                    if (f4 == 0) atomicAdd(&cnts[g0 + curli], cnt);
                }
            }
            acc.x = acc.y = acc.z = acc.w = 0.f; cnt = 0.f; curli = li;
        }
        float4 v = H4[(long long)node * 4 + f4];
        acc.x += v.x; acc.y += v.y; acc.z += v.z; acc.w += v.w;
        cnt += 1.f;
    }
    if (curli >= 0) {
        if (curli < 16) {
            float* bp = &sBin[curli][f4 * 4];
            atomicAdd(bp + 0, acc.x); atomicAdd(bp + 1, acc.y);
            atomicAdd(bp + 2, acc.z); atomicAdd(bp + 3, acc.w);
            if (f4 == 0) atomicAdd(&sCnt[curli], cnt);
        } else {
            float* gp = &sums[(g0 + curli) * OUTF + f4 * 4];
            atomicAdd(gp + 0, acc.x); atomicAdd(gp + 1, acc.y);
            atomicAdd(gp + 2, acc.z); atomicAdd(gp + 3, acc.w);
            if (f4 == 0) atomicAdd(&cnts[g0 + curli], cnt);
        }
    }
    __syncthreads();
    int bg = t >> 4, bf = t & 15;
    int g = g0 + bg;
    if (g < NGRAPH) {
        float v = sBin[bg][bf];
        if (v != 0.f) atomicAdd(&sums[g * OUTF + bf], v);
        if (bf == 0) {
            float c = sCnt[bg];
            if (c != 0.f) atomicAdd(&cnts[g], c);
        }
    }
}

__global__ void divide_kernel(const float* __restrict__ sums, const float* __restrict__ counts,
                              float* __restrict__ out) {
    int i = blockIdx.x * blockDim.x + threadIdx.x;
    if (i < NGRAPH * OUTF) out[i] = sums[i] / fmaxf(counts[i >> 4], 1.0f);
}

extern "C" void kernel_launch(void* const* d_in, const int* in_sizes, int n_in,
                              void* d_out, int out_size, void* d_ws, size_t ws_size,
                              hipStream_t stream) {
    const float* x     = (const float*)d_in[0];
    const int*   ei    = (const int*)d_in[1];
    const int*   batch = (const int*)d_in[2];
    const float* W1 = (const float*)d_in[3];
    const float* b1 = (const float*)d_in[4];
    const float* W2 = (const float*)d_in[5];
    const float* b2 = (const float*)d_in[6];
    const float* W3 = (const float*)d_in[7];
    const float* b3 = (const float*)d_in[8];
    float* out = (float*)d_out;

    const int N = in_sizes[2];          // 100000
    const int E = in_sizes[1] / 2;      // 1200000
    const int* src = ei;
    const int* dst = ei + E;

    // workspace layout (4-byte units)
    float* ws      = (float*)d_ws;
    float* dis     = ws;                          // N floats
    float* bufA    = dis + N;                     // N*64
    float* bufB    = bufA + (size_t)N * HID;      // N*64
    float* sums    = bufB + (size_t)N * HID;      // 500*16
    float* cnts    = sums + NGRAPH * OUTF;        // 500
    int*   degi    = (int*)(cnts + NGRAPH);       // N ints
    int*   rowptr  = degi + N;                    // N ints
    int*   csr_src = rowptr + N;                  // E ints
    int*   aux     = csr_src + E;                 // <=128 ints

    const int B = 256;
    const int nb = (N + 1023) / 1024;
    constexpr int EPT = 4;
    const int eblocks = (E + B * EPT - 1) / (B * EPT);

    // ---- degree, dis, rowptr scan ----
    hipMemsetAsync(degi, 0, (size_t)N * sizeof(int), stream);
    deg_kernel<EPT><<<eblocks, B, 0, stream>>>(dst, degi, E);
    scan1_kernel<<<nb, 1024, 0, stream>>>(degi, rowptr, aux, dis, N);
    scan2_kernel<<<1, 128, 0, stream>>>(aux, nb);
    scan3_kernel<<<nb, 1024, 0, stream>>>(rowptr, aux, N);

    // ---- CSR fill co-scheduled with gemm1 (independent work) ----
    const int gemm1Blocks = (N + 15) / 16;
    fill_gemm_kernel<<<eblocks + gemm1Blocks, B, 0, stream>>>(
        src, dst, rowptr, csr_src, E, eblocks, x, W1, bufA, N);

    // ---- layer 1 aggregate ----
    agg64_kernel<true><<<(N + 3) / 4, B, 0, stream>>>((const float4*)bufA, rowptr, csr_src,
                                                      dis, (const float4*)b1, (float4*)bufB, N);

    // ---- layer 2 ----
    gemm_kernel<HID, HID><<<(N + 15) / 16, B, 0, stream>>>(bufB, W2, bufA, N);
    agg64_kernel<true><<<(N + 3) / 4, B, 0, stream>>>((const float4*)bufA, rowptr, csr_src,
                                                      dis, (const float4*)b2, (float4*)bufB, N);

    // ---- layer 3 ----
    gemm_kernel<HID, OUTF><<<(N + 63) / 64, B, 0, stream>>>(bufB, W3, bufA, N);
    agg16_kernel<false><<<(N + 3) / 4, B, 0, stream>>>((const float4*)bufA, rowptr, csr_src,
                                                       dis, (const float4*)b3, (float4*)bufB, N);

    // ---- global mean pool ----
    hipMemsetAsync(sums, 0, (NGRAPH * OUTF + NGRAPH) * sizeof(float), stream);
    pool_kernel<<<(N + 255) / 256, B, 0, stream>>>((const float4*)bufB, batch, sums, cnts, N);
    divide_kernel<<<(NGRAPH * OUTF + B - 1) / B, B, 0, stream>>>(sums, cnts, out);
}

// Round 6
// 434.215 us; speedup vs baseline: 1.1454x; 1.1454x over previous
//
#include <hip/hip_runtime.h>
#include <hip/hip_bf16.h>

#define IN_DIM 128
#define HID    64
#define OUTF   16
#define NGRAPH 500

// ---------------- GEMM: H[N,F] = X[N,K] @ W[K,F] ----------------
template<int K, int F>
__global__ __launch_bounds__(256) void gemm_kernel(const float* __restrict__ X,
                                                   const float* __restrict__ W,
                                                   float* __restrict__ H, int N) {
    constexpr int C4 = F / 4;          // float4 cols
    constexpr int ROWS = 256 / C4;     // rows per block
    constexpr int K4 = K / 4;
    __shared__ float4 sW[K * C4];
    __shared__ float4 sX4[ROWS * K4];
    const int tid = threadIdx.x;
    const float4* W4 = (const float4*)W;
    for (int i = tid; i < K * C4; i += 256) sW[i] = W4[i];
    const int row0 = blockIdx.x * ROWS;
    const float4* X4 = (const float4*)X;
    for (int i = tid; i < ROWS * K4; i += 256) {
        int r = i / K4, kk = i - r * K4;
        int gr = row0 + r;
        float4 z = {0.f, 0.f, 0.f, 0.f};
        sX4[r * K4 + kk] = (gr < N) ? X4[(long long)gr * K4 + kk] : z;
    }
    __syncthreads();
    const int r = tid / C4, c4 = tid - (tid / C4) * C4;
    const float* sXr = (const float*)&sX4[r * K4];
    float4 acc = {0.f, 0.f, 0.f, 0.f};
#pragma unroll
    for (int k = 0; k < K; ++k) {
        float xv = sXr[k];
        float4 wv = sW[k * C4 + c4];
        acc.x += xv * wv.x; acc.y += xv * wv.y;
        acc.z += xv * wv.z; acc.w += xv * wv.w;
    }
    const int gr = row0 + r;
    if (gr < N) ((float4*)H)[(long long)gr * C4 + c4] = acc;
}

// ---------------- degree (int), 8 edges/thread ----------------
template<int EPT>
__global__ __launch_bounds__(256) void deg_kernel(const int* __restrict__ dst,
                                                  int* __restrict__ degi, int E) {
    int base = blockIdx.x * (256 * EPT) + threadIdx.x;
    if (base + (EPT - 1) * 256 < E) {
        int d[EPT];
#pragma unroll
        for (int k = 0; k < EPT; ++k) d[k] = dst[base + k * 256];
#pragma unroll
        for (int k = 0; k < EPT; ++k) atomicAdd(&degi[d[k]], 1);
    } else {
#pragma unroll
        for (int k = 0; k < EPT; ++k) {
            int e = base + k * 256;
            if (e < E) atomicAdd(&degi[dst[e]], 1);
        }
    }
}

// ---------------- scan1: exclusive block-scan of degi; also emits dis ----------
__global__ __launch_bounds__(1024) void scan1_kernel(const int* __restrict__ degi,
                                                     int* __restrict__ rowptr,
                                                     int* __restrict__ aux,
                                                     float* __restrict__ dis, int N) {
    __shared__ int s[1024];
    int i = blockIdx.x * 1024 + threadIdx.x;
    int v = (i < N) ? degi[i] : 0;
    if (i < N) dis[i] = rsqrtf(1.0f + (float)v);
    s[threadIdx.x] = v;
    __syncthreads();
    for (int off = 1; off < 1024; off <<= 1) {
        int t = (threadIdx.x >= off) ? s[threadIdx.x - off] : 0;
        __syncthreads();
        s[threadIdx.x] += t;
        __syncthreads();
    }
    if (i < N) rowptr[i] = s[threadIdx.x] - v;          // exclusive
    if (threadIdx.x == 1023) aux[blockIdx.x] = s[1023]; // block total
}

__global__ __launch_bounds__(128) void scan2_kernel(int* __restrict__ aux, int nb) {
    __shared__ int s[128];
    int v = (threadIdx.x < nb) ? aux[threadIdx.x] : 0;
    s[threadIdx.x] = v;
    __syncthreads();
    for (int off = 1; off < 128; off <<= 1) {
        int t = (threadIdx.x >= off) ? s[threadIdx.x - off] : 0;
        __syncthreads();
        s[threadIdx.x] += t;
        __syncthreads();
    }
    if (threadIdx.x < nb) aux[threadIdx.x] = s[threadIdx.x] - v; // exclusive
}

__global__ __launch_bounds__(1024) void scan3_kernel(int* __restrict__ rowptr,
                                                     const int* __restrict__ aux, int N) {
    int i = blockIdx.x * 1024 + threadIdx.x;
    if (i < N) rowptr[i] += aux[blockIdx.x];
}

// ---------------- range-partitioned CSR fill ----------------
// R4: fill's cost is WRITE_SIZE=84MB = full-line writeback per scattered 4B
// store, amplified by partial dirty copies in multiple non-coherent XCD L2s.
// Block b handles only dst range (b&7); under round-robin block->XCD dispatch
// all writers of a range share an XCD, so a line's ~16 stores coalesce in one
// L2 before writeback. Trade: 8x re-scan of the L3-resident dst array.
// Correctness does NOT depend on the XCD mapping (device-scope atomics,
// unique store addresses).
template<int EPT>
__global__ __launch_bounds__(256) void fill_kernel(const int* __restrict__ src,
                                                   const int* __restrict__ dst,
                                                   int* __restrict__ rowptr,
                                                   int* __restrict__ csr_src,
                                                   int E, int rangeSize) {
    const int range = blockIdx.x & 7;
    const int lo = range * rangeSize;
    const int hi = lo + rangeSize;           // exclusive
    int base = (blockIdx.x >> 3) * (256 * EPT) + threadIdx.x;
#pragma unroll
    for (int k = 0; k < EPT; ++k) {
        int e = base + k * 256;
        if (e < E) {
            int d = dst[e];
            if (d >= lo && d < hi) {
                int pos = atomicAdd(&rowptr[d], 1);
                csr_src[pos] = src[e];
            }
        }
    }
}

// ---------------- fused aggregate + self-loop + bias [+ relu], F=64 ----------------
// Wave = one node. 8 edge-groups x 8 lanes x 32B/lane: 8 edges in flight.
template<bool RELU>
__global__ __launch_bounds__(256) void agg64_kernel(const float4* __restrict__ H4,
                                                    const int* __restrict__ rowptr,
                                                    const int* __restrict__ csr_src,
                                                    const float* __restrict__ dis,
                                                    const float4* __restrict__ b4,
                                                    float4* __restrict__ out4, int N) {
    int node = blockIdx.x * 4 + (threadIdx.x >> 6);
    int lane = threadIdx.x & 63;
    int g = lane >> 3, c = lane & 7;   // group, chunk-pair index
    if (node >= N) return;
    float dd = dis[node];
    int i0 = (node == 0) ? 0 : rowptr[node - 1];
    int i1 = rowptr[node];
    float4 a0 = {0.f, 0.f, 0.f, 0.f}, a1 = {0.f, 0.f, 0.f, 0.f};
    for (int i = i0 + g; i < i1; i += 8) {
        int s = csr_src[i];
        float w = dis[s] * dd;
        float4 v0 = H4[(long long)s * 16 + 2 * c];
        float4 v1 = H4[(long long)s * 16 + 2 * c + 1];
        a0.x += v0.x * w; a0.y += v0.y * w; a0.z += v0.z * w; a0.w += v0.w * w;
        a1.x += v1.x * w; a1.y += v1.y * w; a1.z += v1.z * w; a1.w += v1.w * w;
    }
#pragma unroll
    for (int m = 8; m <= 32; m <<= 1) {
        a0.x += __shfl_xor(a0.x, m); a0.y += __shfl_xor(a0.y, m);
        a0.z += __shfl_xor(a0.z, m); a0.w += __shfl_xor(a0.w, m);
        a1.x += __shfl_xor(a1.x, m); a1.y += __shfl_xor(a1.y, m);
        a1.z += __shfl_xor(a1.z, m); a1.w += __shfl_xor(a1.w, m);
    }
    if (g == 0) {
        float sl = dd * dd;
        float4 h0 = H4[(long long)node * 16 + 2 * c];
        float4 h1 = H4[(long long)node * 16 + 2 * c + 1];
        float4 bb0 = b4[2 * c], bb1 = b4[2 * c + 1];
        a0.x += h0.x * sl + bb0.x; a0.y += h0.y * sl + bb0.y;
        a0.z += h0.z * sl + bb0.z; a0.w += h0.w * sl + bb0.w;
        a1.x += h1.x * sl + bb1.x; a1.y += h1.y * sl + bb1.y;
        a1.z += h1.z * sl + bb1.z; a1.w += h1.w * sl + bb1.w;
        if (RELU) {
            a0.x = fmaxf(a0.x, 0.f); a0.y = fmaxf(a0.y, 0.f);
            a0.z = fmaxf(a0.z, 0.f); a0.w = fmaxf(a0.w, 0.f);
            a1.x = fmaxf(a1.x, 0.f); a1.y = fmaxf(a1.y, 0.f);
            a1.z = fmaxf(a1.z, 0.f); a1.w = fmaxf(a1.w, 0.f);
        }
        out4[(long long)node * 16 + 2 * c] = a0;
        out4[(long long)node * 16 + 2 * c + 1] = a1;
    }
}

// ---------------- F=16: 16 edge-groups x 4 chunks per wave ----------------
template<bool RELU>
__global__ __launch_bounds__(256) void agg16_kernel(const float4* __restrict__ H4,
                                                    const int* __restrict__ rowptr,
                                                    const int* __restrict__ csr_src,
                                                    const float* __restrict__ dis,
                                                    const float4* __restrict__ b4,
                                                    float4* __restrict__ out4, int N) {
    int node = blockIdx.x * 4 + (threadIdx.x >> 6);
    int lane = threadIdx.x & 63;
    int g = lane >> 2, c = lane & 3;
    if (node >= N) return;
    float dd = dis[node];
    int i0 = (node == 0) ? 0 : rowptr[node - 1];
    int i1 = rowptr[node];
    float4 acc = {0.f, 0.f, 0.f, 0.f};
    for (int i = i0 + g; i < i1; i += 16) {
        int s = csr_src[i];
        float w = dis[s] * dd;
        float4 v = H4[(long long)s * 4 + c];
        acc.x += v.x * w; acc.y += v.y * w;
        acc.z += v.z * w; acc.w += v.w * w;
    }
#pragma unroll
    for (int m = 4; m <= 32; m <<= 1) {
        acc.x += __shfl_xor(acc.x, m);
        acc.y += __shfl_xor(acc.y, m);
        acc.z += __shfl_xor(acc.z, m);
        acc.w += __shfl_xor(acc.w, m);
    }
    if (g == 0) {
        float4 h = H4[(long long)node * 4 + c];
        float sl = dd * dd;
        float4 bb = b4[c];
        acc.x += h.x * sl + bb.x; acc.y += h.y * sl + bb.y;
        acc.z += h.z * sl + bb.z; acc.w += h.w * sl + bb.w;
        if (RELU) {
            acc.x = fmaxf(acc.x, 0.f); acc.y = fmaxf(acc.y, 0.f);
            acc.z = fmaxf(acc.z, 0.f); acc.w = fmaxf(acc.w, 0.f);
        }
        out4[(long long)node * 4 + c] = acc;
    }
}

// ---------------- pooling: register runs -> LDS bins -> few global atomics ----
__global__ __launch_bounds__(256) void pool_kernel(const float4* __restrict__ H4,
                                                   const int* __restrict__ batch,
                                                   float* __restrict__ sums,
                                                   float* __restrict__ cnts, int N) {
    __shared__ float sBin[16][16];
    __shared__ float sCnt[16];
    const int t = threadIdx.x;
    sBin[t >> 4][t & 15] = 0.f;
    if (t < 16) sCnt[t] = 0.f;
    __syncthreads();
    const int n0 = blockIdx.x * 256;
    const int g0 = batch[n0];
    const int nl = t >> 2;     // node lane 0..63
    const int f4 = t & 3;      // float4 chunk 0..3
    float4 acc = {0.f, 0.f, 0.f, 0.f};
    float cnt = 0.f;
    int curli = -1;
    for (int j = 0; j < 4; ++j) {
        int node = n0 + nl * 4 + j;
        if (node >= N) break;
        int li = batch[node] - g0;
        if (li != curli) {
            if (curli >= 0) {
                if (curli < 16) {
                    float* bp = &sBin[curli][f4 * 4];
                    atomicAdd(bp + 0, acc.x); atomicAdd(bp + 1, acc.y);
                    atomicAdd(bp + 2, acc.z); atomicAdd(bp + 3, acc.w);
                    if (f4 == 0) atomicAdd(&sCnt[curli], cnt);
                } else {
                    float* gp = &sums[(g0 + curli) * OUTF + f4 * 4];
                    atomicAdd(gp + 0, acc.x); atomicAdd(gp + 1, acc.y);
                    atomicAdd(gp + 2, acc.z); atomicAdd(gp + 3, acc.w);
                    if (f4 == 0) atomicAdd(&cnts[g0 + curli], cnt);
                }
            }
            acc.x = acc.y = acc.z = acc.w = 0.f; cnt = 0.f; curli = li;
        }
        float4 v = H4[(long long)node * 4 + f4];
        acc.x += v.x; acc.y += v.y; acc.z += v.z; acc.w += v.w;
        cnt += 1.f;
    }
    if (curli >= 0) {
        if (curli < 16) {
            float* bp = &sBin[curli][f4 * 4];
            atomicAdd(bp + 0, acc.x); atomicAdd(bp + 1, acc.y);
            atomicAdd(bp + 2, acc.z); atomicAdd(bp + 3, acc.w);
            if (f4 == 0) atomicAdd(&sCnt[curli], cnt);
        } else {
            float* gp = &sums[(g0 + curli) * OUTF + f4 * 4];
            atomicAdd(gp + 0, acc.x); atomicAdd(gp + 1, acc.y);
            atomicAdd(gp + 2, acc.z); atomicAdd(gp + 3, acc.w);
            if (f4 == 0) atomicAdd(&cnts[g0 + curli], cnt);
        }
    }
    __syncthreads();
    int bg = t >> 4, bf = t & 15;
    int g = g0 + bg;
    if (g < NGRAPH) {
        float v = sBin[bg][bf];
        if (v != 0.f) atomicAdd(&sums[g * OUTF + bf], v);
        if (bf == 0) {
            float c = sCnt[bg];
            if (c != 0.f) atomicAdd(&cnts[g], c);
        }
    }
}

__global__ void divide_kernel(const float* __restrict__ sums, const float* __restrict__ counts,
                              float* __restrict__ out) {
    int i = blockIdx.x * blockDim.x + threadIdx.x;
    if (i < NGRAPH * OUTF) out[i] = sums[i] / fmaxf(counts[i >> 4], 1.0f);
}

extern "C" void kernel_launch(void* const* d_in, const int* in_sizes, int n_in,
                              void* d_out, int out_size, void* d_ws, size_t ws_size,
                              hipStream_t stream) {
    const float* x     = (const float*)d_in[0];
    const int*   ei    = (const int*)d_in[1];
    const int*   batch = (const int*)d_in[2];
    const float* W1 = (const float*)d_in[3];
    const float* b1 = (const float*)d_in[4];
    const float* W2 = (const float*)d_in[5];
    const float* b2 = (const float*)d_in[6];
    const float* W3 = (const float*)d_in[7];
    const float* b3 = (const float*)d_in[8];
    float* out = (float*)d_out;

    const int N = in_sizes[2];          // 100000
    const int E = in_sizes[1] / 2;      // 1200000
    const int* src = ei;
    const int* dst = ei + E;

    // workspace layout (4-byte units)
    float* ws      = (float*)d_ws;
    float* dis     = ws;                          // N floats
    float* bufA    = dis + N;                     // N*64
    float* bufB    = bufA + (size_t)N * HID;      // N*64
    float* sums    = bufB + (size_t)N * HID;      // 500*16
    float* cnts    = sums + NGRAPH * OUTF;        // 500
    int*   degi    = (int*)(cnts + NGRAPH);       // N ints
    int*   rowptr  = degi + N;                    // N ints
    int*   csr_src = rowptr + N;                  // E ints
    int*   aux     = csr_src + E;                 // <=128 ints

    const int B = 256;
    const int nb = (N + 1023) / 1024;

    // ---- degree, dis, rowptr scan ----
    hipMemsetAsync(degi, 0, (size_t)N * sizeof(int), stream);
    deg_kernel<8><<<(E + B * 8 - 1) / (B * 8), B, 0, stream>>>(dst, degi, E);
    scan1_kernel<<<nb, 1024, 0, stream>>>(degi, rowptr, aux, dis, N);
    scan2_kernel<<<1, 128, 0, stream>>>(aux, nb);
    scan3_kernel<<<nb, 1024, 0, stream>>>(rowptr, aux, N);

    // ---- range-partitioned CSR fill ----
    {
        constexpr int EPT = 8;
        const int chunks = (E + B * EPT - 1) / (B * EPT);
        const int rangeSize = (N + 7) / 8;
        fill_kernel<EPT><<<chunks * 8, B, 0, stream>>>(src, dst, rowptr, csr_src, E, rangeSize);
    }

    // ---- layer 1 ----
    gemm_kernel<IN_DIM, HID><<<(N + 15) / 16, B, 0, stream>>>(x, W1, bufA, N);
    agg64_kernel<true><<<(N + 3) / 4, B, 0, stream>>>((const float4*)bufA, rowptr, csr_src,
                                                      dis, (const float4*)b1, (float4*)bufB, N);

    // ---- layer 2 ----
    gemm_kernel<HID, HID><<<(N + 15) / 16, B, 0, stream>>>(bufB, W2, bufA, N);
    agg64_kernel<true><<<(N + 3) / 4, B, 0, stream>>>((const float4*)bufA, rowptr, csr_src,
                                                      dis, (const float4*)b2, (float4*)bufB, N);

    // ---- layer 3 ----
    gemm_kernel<HID, OUTF><<<(N + 63) / 64, B, 0, stream>>>(bufB, W3, bufA, N);
    agg16_kernel<false><<<(N + 3) / 4, B, 0, stream>>>((const float4*)bufA, rowptr, csr_src,
                                                       dis, (const float4*)b3, (float4*)bufB, N);

    // ---- global mean pool ----
    hipMemsetAsync(sums, 0, (NGRAPH * OUTF + NGRAPH) * sizeof(float), stream);
    pool_kernel<<<(N + 255) / 256, B, 0, stream>>>((const float4*)bufB, batch, sums, cnts, N);
    divide_kernel<<<(NGRAPH * OUTF + B - 1) / B, B, 0, stream>>>(sums, cnts, out);
}

// Round 7
// 418.091 us; speedup vs baseline: 1.1896x; 1.0386x over previous
//
#include <hip/hip_runtime.h>
#include <hip/hip_bf16.h>

#define IN_DIM 128
#define HID    64
#define OUTF   16
#define NGRAPH 500

// ---------------- register-tiled GEMM, F=64: H[N,64] = X[N,K] @ W[K,64] -------
// Block = 64 rows x 64 cols; thread = 4 rows x 4 cols. Per k: 1 ds_read_b128
// (W) + 4 broadcast ds_read_b32 (X) for 16 FMAs. sX rows padded to K+4 floats
// (528 B for K=128): row-group addresses hit banks {0,16} -> 2-way = free.
template<int K>
__global__ __launch_bounds__(256) void gemm64_kernel(const float* __restrict__ X,
                                                     const float* __restrict__ W,
                                                     float* __restrict__ H, int N) {
    constexpr int PAD = 4;
    constexpr int LDX = K + PAD;           // floats per sX row
    constexpr int K4 = K / 4;
    __shared__ float sX[64 * LDX];
    __shared__ float sW[K * 64];
    const int tid = threadIdx.x;
    const int row0 = blockIdx.x * 64;

    // stage W: K*16 float4, coalesced
    const float4* W4 = (const float4*)W;
    float4* sW4 = (float4*)sW;
    for (int i = tid; i < K * 16; i += 256) sW4[i] = W4[i];
    // stage X: 64 rows x K4 float4
    const float4* X4 = (const float4*)X;
    for (int i = tid; i < 64 * K4; i += 256) {
        int r = i / K4, kk = i - r * K4;
        int gr = row0 + r;
        float4 v = {0.f, 0.f, 0.f, 0.f};
        if (gr < N) v = X4[(long long)gr * K4 + kk];
        *(float4*)&sX[r * LDX + kk * 4] = v;
    }
    __syncthreads();

    const int tc = tid & 15;               // col group (float4)
    const int tr = tid >> 4;               // row group (4 rows)
    const float* sX0 = &sX[(tr * 4) * LDX];
    float4 acc0 = {0,0,0,0}, acc1 = {0,0,0,0}, acc2 = {0,0,0,0}, acc3 = {0,0,0,0};
#pragma unroll 8
    for (int k = 0; k < K; ++k) {
        float4 wv = ((const float4*)sW)[k * 16 + tc];
        float a0 = sX0[k];
        float a1 = sX0[LDX + k];
        float a2 = sX0[2 * LDX + k];
        float a3 = sX0[3 * LDX + k];
        acc0.x += a0 * wv.x; acc0.y += a0 * wv.y; acc0.z += a0 * wv.z; acc0.w += a0 * wv.w;
        acc1.x += a1 * wv.x; acc1.y += a1 * wv.y; acc1.z += a1 * wv.z; acc1.w += a1 * wv.w;
        acc2.x += a2 * wv.x; acc2.y += a2 * wv.y; acc2.z += a2 * wv.z; acc2.w += a2 * wv.w;
        acc3.x += a3 * wv.x; acc3.y += a3 * wv.y; acc3.z += a3 * wv.z; acc3.w += a3 * wv.w;
    }
    float4* H4 = (float4*)H;
    int r0 = row0 + tr * 4;
    if (r0 + 0 < N) H4[(long long)(r0 + 0) * 16 + tc] = acc0;
    if (r0 + 1 < N) H4[(long long)(r0 + 1) * 16 + tc] = acc1;
    if (r0 + 2 < N) H4[(long long)(r0 + 2) * 16 + tc] = acc2;
    if (r0 + 3 < N) H4[(long long)(r0 + 3) * 16 + tc] = acc3;
}

// ---------------- GEMM, F=16 (layer 3): old structure + sX pad ----------------
template<int K, int F>
__global__ __launch_bounds__(256) void gemm_kernel(const float* __restrict__ X,
                                                   const float* __restrict__ W,
                                                   float* __restrict__ H, int N) {
    constexpr int C4 = F / 4;          // float4 cols
    constexpr int ROWS = 256 / C4;     // rows per block
    constexpr int K4 = K / 4;
    constexpr int LDX4 = K4 + 1;       // pad one float4: stride 272B kills 16-way
    __shared__ float4 sW[K * C4];
    __shared__ float4 sX4[ROWS * LDX4];
    const int tid = threadIdx.x;
    const float4* W4 = (const float4*)W;
    for (int i = tid; i < K * C4; i += 256) sW[i] = W4[i];
    const int row0 = blockIdx.x * ROWS;
    const float4* X4 = (const float4*)X;
    for (int i = tid; i < ROWS * K4; i += 256) {
        int r = i / K4, kk = i - r * K4;
        int gr = row0 + r;
        float4 z = {0.f, 0.f, 0.f, 0.f};
        sX4[r * LDX4 + kk] = (gr < N) ? X4[(long long)gr * K4 + kk] : z;
    }
    __syncthreads();
    const int r = tid / C4, c4 = tid - (tid / C4) * C4;
    const float* sXr = (const float*)&sX4[r * LDX4];
    float4 acc = {0.f, 0.f, 0.f, 0.f};
#pragma unroll
    for (int k = 0; k < K; ++k) {
        float xv = sXr[k];
        float4 wv = sW[k * C4 + c4];
        acc.x += xv * wv.x; acc.y += xv * wv.y;
        acc.z += xv * wv.z; acc.w += xv * wv.w;
    }
    const int gr = row0 + r;
    if (gr < N) ((float4*)H)[(long long)gr * C4 + c4] = acc;
}

// ---------------- degree (int), 8 edges/thread ----------------
template<int EPT>
__global__ __launch_bounds__(256) void deg_kernel(const int* __restrict__ dst,
                                                  int* __restrict__ degi, int E) {
    int base = blockIdx.x * (256 * EPT) + threadIdx.x;
    if (base + (EPT - 1) * 256 < E) {
        int d[EPT];
#pragma unroll
        for (int k = 0; k < EPT; ++k) d[k] = dst[base + k * 256];
#pragma unroll
        for (int k = 0; k < EPT; ++k) atomicAdd(&degi[d[k]], 1);
    } else {
#pragma unroll
        for (int k = 0; k < EPT; ++k) {
            int e = base + k * 256;
            if (e < E) atomicAdd(&degi[dst[e]], 1);
        }
    }
}

// ---------------- scan1: exclusive block-scan of degi; also emits dis ----------
__global__ __launch_bounds__(1024) void scan1_kernel(const int* __restrict__ degi,
                                                     int* __restrict__ rowptr,
                                                     int* __restrict__ aux,
                                                     float* __restrict__ dis, int N) {
    __shared__ int s[1024];
    int i = blockIdx.x * 1024 + threadIdx.x;
    int v = (i < N) ? degi[i] : 0;
    if (i < N) dis[i] = rsqrtf(1.0f + (float)v);
    s[threadIdx.x] = v;
    __syncthreads();
    for (int off = 1; off < 1024; off <<= 1) {
        int t = (threadIdx.x >= off) ? s[threadIdx.x - off] : 0;
        __syncthreads();
        s[threadIdx.x] += t;
        __syncthreads();
    }
    if (i < N) rowptr[i] = s[threadIdx.x] - v;          // exclusive
    if (threadIdx.x == 1023) aux[blockIdx.x] = s[1023]; // block total
}

__global__ __launch_bounds__(128) void scan2_kernel(int* __restrict__ aux, int nb) {
    __shared__ int s[128];
    int v = (threadIdx.x < nb) ? aux[threadIdx.x] : 0;
    s[threadIdx.x] = v;
    __syncthreads();
    for (int off = 1; off < 128; off <<= 1) {
        int t = (threadIdx.x >= off) ? s[threadIdx.x - off] : 0;
        __syncthreads();
        s[threadIdx.x] += t;
        __syncthreads();
    }
    if (threadIdx.x < nb) aux[threadIdx.x] = s[threadIdx.x] - v; // exclusive
}

__global__ __launch_bounds__(1024) void scan3_kernel(int* __restrict__ rowptr,
                                                     const int* __restrict__ aux, int N) {
    int i = blockIdx.x * 1024 + threadIdx.x;
    if (i < N) rowptr[i] += aux[blockIdx.x];
}

// ---------------- range-partitioned CSR fill (see R5 note) ----------------
template<int EPT>
__global__ __launch_bounds__(256) void fill_kernel(const int* __restrict__ src,
                                                   const int* __restrict__ dst,
                                                   int* __restrict__ rowptr,
                                                   int* __restrict__ csr_src,
                                                   int E, int rangeSize) {
    const int range = blockIdx.x & 7;
    const int lo = range * rangeSize;
    const int hi = lo + rangeSize;           // exclusive
    int base = (blockIdx.x >> 3) * (256 * EPT) + threadIdx.x;
#pragma unroll
    for (int k = 0; k < EPT; ++k) {
        int e = base + k * 256;
        if (e < E) {
            int d = dst[e];
            if (d >= lo && d < hi) {
                int pos = atomicAdd(&rowptr[d], 1);
                csr_src[pos] = src[e];
            }
        }
    }
}

// ---------------- fused aggregate + self-loop + bias [+ relu], F=64 ----------------
template<bool RELU>
__global__ __launch_bounds__(256) void agg64_kernel(const float4* __restrict__ H4,
                                                    const int* __restrict__ rowptr,
                                                    const int* __restrict__ csr_src,
                                                    const float* __restrict__ dis,
                                                    const float4* __restrict__ b4,
                                                    float4* __restrict__ out4, int N) {
    int node = blockIdx.x * 4 + (threadIdx.x >> 6);
    int lane = threadIdx.x & 63;
    int g = lane >> 3, c = lane & 7;   // group, chunk-pair index
    if (node >= N) return;
    float dd = dis[node];
    int i0 = (node == 0) ? 0 : rowptr[node - 1];
    int i1 = rowptr[node];
    float4 a0 = {0.f, 0.f, 0.f, 0.f}, a1 = {0.f, 0.f, 0.f, 0.f};
    for (int i = i0 + g; i < i1; i += 8) {
        int s = csr_src[i];
        float w = dis[s] * dd;
        float4 v0 = H4[(long long)s * 16 + 2 * c];
        float4 v1 = H4[(long long)s * 16 + 2 * c + 1];
        a0.x += v0.x * w; a0.y += v0.y * w; a0.z += v0.z * w; a0.w += v0.w * w;
        a1.x += v1.x * w; a1.y += v1.y * w; a1.z += v1.z * w; a1.w += v1.w * w;
    }
#pragma unroll
    for (int m = 8; m <= 32; m <<= 1) {
        a0.x += __shfl_xor(a0.x, m); a0.y += __shfl_xor(a0.y, m);
        a0.z += __shfl_xor(a0.z, m); a0.w += __shfl_xor(a0.w, m);
        a1.x += __shfl_xor(a1.x, m); a1.y += __shfl_xor(a1.y, m);
        a1.z += __shfl_xor(a1.z, m); a1.w += __shfl_xor(a1.w, m);
    }
    if (g == 0) {
        float sl = dd * dd;
        float4 h0 = H4[(long long)node * 16 + 2 * c];
        float4 h1 = H4[(long long)node * 16 + 2 * c + 1];
        float4 bb0 = b4[2 * c], bb1 = b4[2 * c + 1];
        a0.x += h0.x * sl + bb0.x; a0.y += h0.y * sl + bb0.y;
        a0.z += h0.z * sl + bb0.z; a0.w += h0.w * sl + bb0.w;
        a1.x += h1.x * sl + bb1.x; a1.y += h1.y * sl + bb1.y;
        a1.z += h1.z * sl + bb1.z; a1.w += h1.w * sl + bb1.w;
        if (RELU) {
            a0.x = fmaxf(a0.x, 0.f); a0.y = fmaxf(a0.y, 0.f);
            a0.z = fmaxf(a0.z, 0.f); a0.w = fmaxf(a0.w, 0.f);
            a1.x = fmaxf(a1.x, 0.f); a1.y = fmaxf(a1.y, 0.f);
            a1.z = fmaxf(a1.z, 0.f); a1.w = fmaxf(a1.w, 0.f);
        }
        out4[(long long)node * 16 + 2 * c] = a0;
        out4[(long long)node * 16 + 2 * c + 1] = a1;
    }
}

// ---------------- F=16: 16 edge-groups x 4 chunks per wave ----------------
template<bool RELU>
__global__ __launch_bounds__(256) void agg16_kernel(const float4* __restrict__ H4,
                                                    const int* __restrict__ rowptr,
                                                    const int* __restrict__ csr_src,
                                                    const float* __restrict__ dis,
                                                    const float4* __restrict__ b4,
                                                    float4* __restrict__ out4, int N) {
    int node = blockIdx.x * 4 + (threadIdx.x >> 6);
    int lane = threadIdx.x & 63;
    int g = lane >> 2, c = lane & 3;
    if (node >= N) return;
    float dd = dis[node];
    int i0 = (node == 0) ? 0 : rowptr[node - 1];
    int i1 = rowptr[node];
    float4 acc = {0.f, 0.f, 0.f, 0.f};
    for (int i = i0 + g; i < i1; i += 16) {
        int s = csr_src[i];
        float w = dis[s] * dd;
        float4 v = H4[(long long)s * 4 + c];
        acc.x += v.x * w; acc.y += v.y * w;
        acc.z += v.z * w; acc.w += v.w * w;
    }
#pragma unroll
    for (int m = 4; m <= 32; m <<= 1) {
        acc.x += __shfl_xor(acc.x, m);
        acc.y += __shfl_xor(acc.y, m);
        acc.z += __shfl_xor(acc.z, m);
        acc.w += __shfl_xor(acc.w, m);
    }
    if (g == 0) {
        float4 h = H4[(long long)node * 4 + c];
        float sl = dd * dd;
        float4 bb = b4[c];
        acc.x += h.x * sl + bb.x; acc.y += h.y * sl + bb.y;
        acc.z += h.z * sl + bb.z; acc.w += h.w * sl + bb.w;
        if (RELU) {
            acc.x = fmaxf(acc.x, 0.f); acc.y = fmaxf(acc.y, 0.f);
            acc.z = fmaxf(acc.z, 0.f); acc.w = fmaxf(acc.w, 0.f);
        }
        out4[(long long)node * 4 + c] = acc;
    }
}

// ---------------- pooling: register runs -> LDS bins -> few global atomics ----
__global__ __launch_bounds__(256) void pool_kernel(const float4* __restrict__ H4,
                                                   const int* __restrict__ batch,
                                                   float* __restrict__ sums,
                                                   float* __restrict__ cnts, int N) {
    __shared__ float sBin[16][16];
    __shared__ float sCnt[16];
    const int t = threadIdx.x;
    sBin[t >> 4][t & 15] = 0.f;
    if (t < 16) sCnt[t] = 0.f;
    __syncthreads();
    const int n0 = blockIdx.x * 256;
    const int g0 = batch[n0];
    const int nl = t >> 2;     // node lane 0..63
    const int f4 = t & 3;      // float4 chunk 0..3
    float4 acc = {0.f, 0.f, 0.f, 0.f};
    float cnt = 0.f;
    int curli = -1;
    for (int j = 0; j < 4; ++j) {
        int node = n0 + nl * 4 + j;
        if (node >= N) break;
        int li = batch[node] - g0;
        if (li != curli) {
            if (curli >= 0) {
                if (curli < 16) {
                    float* bp = &sBin[curli][f4 * 4];
                    atomicAdd(bp + 0, acc.x); atomicAdd(bp + 1, acc.y);
                    atomicAdd(bp + 2, acc.z); atomicAdd(bp + 3, acc.w);
                    if (f4 == 0) atomicAdd(&sCnt[curli], cnt);
                } else {
                    float* gp = &sums[(g0 + curli) * OUTF + f4 * 4];
                    atomicAdd(gp + 0, acc.x); atomicAdd(gp + 1, acc.y);
                    atomicAdd(gp + 2, acc.z); atomicAdd(gp + 3, acc.w);
                    if (f4 == 0) atomicAdd(&cnts[g0 + curli], cnt);
                }
            }
            acc.x = acc.y = acc.z = acc.w = 0.f; cnt = 0.f; curli = li;
        }
        float4 v = H4[(long long)node * 4 + f4];
        acc.x += v.x; acc.y += v.y; acc.z += v.z; acc.w += v.w;
        cnt += 1.f;
    }
    if (curli >= 0) {
        if (curli < 16) {
            float* bp = &sBin[curli][f4 * 4];
            atomicAdd(bp + 0, acc.x); atomicAdd(bp + 1, acc.y);
            atomicAdd(bp + 2, acc.z); atomicAdd(bp + 3, acc.w);
            if (f4 == 0) atomicAdd(&sCnt[curli], cnt);
        } else {
            float* gp = &sums[(g0 + curli) * OUTF + f4 * 4];
            atomicAdd(gp + 0, acc.x); atomicAdd(gp + 1, acc.y);
            atomicAdd(gp + 2, acc.z); atomicAdd(gp + 3, acc.w);
            if (f4 == 0) atomicAdd(&cnts[g0 + curli], cnt);
        }
    }
    __syncthreads();
    int bg = t >> 4, bf = t & 15;
    int g = g0 + bg;
    if (g < NGRAPH) {
        float v = sBin[bg][bf];
        if (v != 0.f) atomicAdd(&sums[g * OUTF + bf], v);
        if (bf == 0) {
            float c = sCnt[bg];
            if (c != 0.f) atomicAdd(&cnts[g], c);
        }
    }
}

__global__ void divide_kernel(const float* __restrict__ sums, const float* __restrict__ counts,
                              float* __restrict__ out) {
    int i = blockIdx.x * blockDim.x + threadIdx.x;
    if (i < NGRAPH * OUTF) out[i] = sums[i] / fmaxf(counts[i >> 4], 1.0f);
}

extern "C" void kernel_launch(void* const* d_in, const int* in_sizes, int n_in,
                              void* d_out, int out_size, void* d_ws, size_t ws_size,
                              hipStream_t stream) {
    const float* x     = (const float*)d_in[0];
    const int*   ei    = (const int*)d_in[1];
    const int*   batch = (const int*)d_in[2];
    const float* W1 = (const float*)d_in[3];
    const float* b1 = (const float*)d_in[4];
    const float* W2 = (const float*)d_in[5];
    const float* b2 = (const float*)d_in[6];
    const float* W3 = (const float*)d_in[7];
    const float* b3 = (const float*)d_in[8];
    float* out = (float*)d_out;

    const int N = in_sizes[2];          // 100000
    const int E = in_sizes[1] / 2;      // 1200000
    const int* src = ei;
    const int* dst = ei + E;

    // workspace layout (4-byte units)
    float* ws      = (float*)d_ws;
    float* dis     = ws;                          // N floats
    float* bufA    = dis + N;                     // N*64
    float* bufB    = bufA + (size_t)N * HID;      // N*64
    float* sums    = bufB + (size_t)N * HID;      // 500*16
    float* cnts    = sums + NGRAPH * OUTF;        // 500
    int*   degi    = (int*)(cnts + NGRAPH);       // N ints
    int*   rowptr  = degi + N;                    // N ints
    int*   csr_src = rowptr + N;                  // E ints
    int*   aux     = csr_src + E;                 // <=128 ints

    const int B = 256;
    const int nb = (N + 1023) / 1024;

    // ---- degree, dis, rowptr scan ----
    hipMemsetAsync(degi, 0, (size_t)N * sizeof(int), stream);
    deg_kernel<8><<<(E + B * 8 - 1) / (B * 8), B, 0, stream>>>(dst, degi, E);
    scan1_kernel<<<nb, 1024, 0, stream>>>(degi, rowptr, aux, dis, N);
    scan2_kernel<<<1, 128, 0, stream>>>(aux, nb);
    scan3_kernel<<<nb, 1024, 0, stream>>>(rowptr, aux, N);

    // ---- range-partitioned CSR fill ----
    {
        constexpr int EPT = 8;
        const int chunks = (E + B * EPT - 1) / (B * EPT);
        const int rangeSize = (N + 7) / 8;
        fill_kernel<EPT><<<chunks * 8, B, 0, stream>>>(src, dst, rowptr, csr_src, E, rangeSize);
    }

    // ---- layer 1 ----
    gemm64_kernel<IN_DIM><<<(N + 63) / 64, B, 0, stream>>>(x, W1, bufA, N);
    agg64_kernel<true><<<(N + 3) / 4, B, 0, stream>>>((const float4*)bufA, rowptr, csr_src,
                                                      dis, (const float4*)b1, (float4*)bufB, N);

    // ---- layer 2 ----
    gemm64_kernel<HID><<<(N + 63) / 64, B, 0, stream>>>(bufB, W2, bufA, N);
    agg64_kernel<true><<<(N + 3) / 4, B, 0, stream>>>((const float4*)bufA, rowptr, csr_src,
                                                      dis, (const float4*)b2, (float4*)bufB, N);

    // ---- layer 3 ----
    gemm_kernel<HID, OUTF><<<(N + 63) / 64, B, 0, stream>>>(bufB, W3, bufA, N);
    agg16_kernel<false><<<(N + 3) / 4, B, 0, stream>>>((const float4*)bufA, rowptr, csr_src,
                                                       dis, (const float4*)b3, (float4*)bufB, N);

    // ---- global mean pool ----
    hipMemsetAsync(sums, 0, (NGRAPH * OUTF + NGRAPH) * sizeof(float), stream);
    pool_kernel<<<(N + 255) / 256, B, 0, stream>>>((const float4*)bufB, batch, sums, cnts, N);
    divide_kernel<<<(NGRAPH * OUTF + B - 1) / B, B, 0, stream>>>(sums, cnts, out);
}